// Round 9
// baseline (297.927 us; speedup 1.0000x reference)
//
#include <hip/hip_runtime.h>

// Problem constants
static constexpr int NN = 10000;   // nodes
static constexpr int DD = 64;      // in/out dim
static constexpr int KP = 10240;   // padded K for M_T
static constexpr int BK = 64;      // K per inner iter
static constexpr int SPLITS = 8;   // K-split factor (grid.y)
static constexpr int KC = KP / SPLITS;  // 1280 K per block
static constexpr int ITERS = KC / BK;   // 20
static constexpr int BM = 64;      // rows per block

typedef __attribute__((ext_vector_type(4))) float f32x4;
typedef __attribute__((ext_vector_type(8))) short s16x8;

__device__ __forceinline__ unsigned short f2bf(float f) {
  // fp32 -> bf16 round-to-nearest-even (bit trick; inputs finite)
  unsigned u = __float_as_uint(f);
  return (unsigned short)((u + 0x7fffu + ((u >> 16) & 1u)) >> 16);
}

// async global->LDS DMA, 16 B per lane: dest = ldsbase + lane*16 (wave-uniform base),
// src per-lane (pre-swizzled global addressing, m173 pattern). Counts 1 in vmcnt.
__device__ __forceinline__ void g2l16(const void* g, void* l) {
  __builtin_amdgcn_global_load_lds((const __attribute__((address_space(1))) unsigned int*)g,
                                   (__attribute__((address_space(3))) unsigned int*)l, 16, 0, 0);
}

// ---------- prep: M_T[r][d][k] = bf16( sum_j H[k][j] * W_r[d][j] ), zero-padded to KP ----------
__global__ void prep_kernel(const float* __restrict__ H,
                            const float* __restrict__ W1,
                            const float* __restrict__ W2,
                            const float* __restrict__ W3,
                            unsigned short* __restrict__ mt) {
  const int r = blockIdx.y;
  const float* W = (r == 0) ? W1 : (r == 1) ? W2 : W3;
  const int wave = threadIdx.x >> 6;
  const int lane = threadIdx.x & 63;   // lane == output dim d
  f32x4 wr[16];
#pragma unroll
  for (int i = 0; i < 16; ++i) wr[i] = *(const f32x4*)&W[lane * 64 + i * 4];
  unsigned short* orow = mt + ((size_t)r * 64 + lane) * KP;
  const int kbase = blockIdx.x * 128 + wave * 32;
  for (int i = 0; i < 32; ++i) {
    const int k = kbase + i;
    if (k < NN) {
      float s = 0.f;
#pragma unroll
      for (int j = 0; j < 16; ++j) {
        f32x4 h = *(const f32x4*)&H[(size_t)k * 64 + j * 4]; // wave-uniform addr -> broadcast
        s += h[0] * wr[j][0] + h[1] * wr[j][1] + h[2] * wr[j][2] + h[3] * wr[j][3];
      }
      orow[k] = f2bf(s);
    } else {
      orow[k] = 0;  // zero pad k in [10000,10240)
    }
  }
}

// ---------- init: out[v][d] = bias[d] ----------
__global__ void init_out_kernel(const float* __restrict__ bias, float* __restrict__ out) {
  const int i = blockIdx.x * 256 + threadIdx.x;
  if (i < NN * DD) out[i] = bias[i & 63];
}

// ---------- main: out += A_r[:, kchunk] @ M_r[kchunk, :]  (bf16 MFMA) ----------
// A streamed via global_load_lds DMA (fp32 tiles -> LDS, swizzled source), cvt to
// bf16 at LDS-read time. M likewise. Double-buffered, counted vmcnt(6), raw
// barriers. Tests whether the DMA path escapes the ~4.1 TB/s reg-load plateau.
__global__ __launch_bounds__(256, 3) void gcn_main(const float* __restrict__ A1,
                                                   const float* __restrict__ A2,
                                                   const float* __restrict__ A3,
                                                   const unsigned short* __restrict__ mt,
                                                   float* __restrict__ out) {
  // A tile: [buf][row][64 floats]; row = 256 B = 16 granules of 16 B; granule g of
  // row stored at slot g ^ (row&15) (via pre-swizzled DMA source; dest linear).
  // M tile: [buf][d][64 bf16]; row = 128 B = 8 granules; slot = g ^ (d&7).
  __shared__ __align__(1024) float          alds [2][64][64];  // 32 KB
  __shared__ __align__(1024) unsigned short mlds2[2][64][64];  // 16 KB

  const int r = blockIdx.z;
  const int s = blockIdx.y;
  const float* A = (r == 0) ? A1 : (r == 1) ? A2 : A3;
  const unsigned short* mtr = mt + (size_t)r * 64 * KP;

  const int wave = threadIdx.x >> 6;
  const int lane = threadIdx.x & 63;
  const int l15 = lane & 15;
  const int lhi = lane >> 4;
  const int v0 = blockIdx.x * BM;
  const int k0 = s * KC;

  f32x4 acc[4] = {{0.f,0.f,0.f,0.f},{0.f,0.f,0.f,0.f},{0.f,0.f,0.f,0.f},{0.f,0.f,0.f,0.f}};

  // ---- A stage: 4 DMA instrs/wave; instr j covers rows 16w+4j..+3 (16 lanes/row) ----
  auto stageA = [&](int t, int buf) {
    const int kb = k0 + t * BK;
#pragma unroll
    for (int j = 0; j < 4; ++j) {
      const int row16 = 4 * j + lhi;                  // row & 15
      int vr = v0 + wave * 16 + row16;
      if (vr > NN - 1) vr = NN - 1;                   // dup rows: results never stored
      int colf = kb + ((l15 ^ row16) << 2);           // pre-swizzled source granule
      if (colf > NN - 4) colf = NN - 4;               // OOB-k dup: killed by M=0 pad
      g2l16(A + (size_t)vr * NN + colf, &alds[buf][wave * 16 + 4 * j][0]);
    }
  };
  // ---- M stage: 2 DMA instrs/wave; instr j covers d-rows 16w+8j..+7 (8 lanes/row) ----
  auto stageM = [&](int t, int buf) {
    const int kb = k0 + t * BK;
#pragma unroll
    for (int j = 0; j < 2; ++j) {
      const int row16 = 8 * j + (lane >> 3);
      const int gsm = (lane & 7) ^ (lane >> 3);       // slot ^ (row&7) involution
      g2l16(mtr + (size_t)(wave * 16 + row16) * KP + kb + gsm * 8,
            &mlds2[buf][wave * 16 + 8 * j][0]);
    }
  };

  auto cvtA = [&](const f32x4& x, const f32x4& y) -> s16x8 {
    s16x8 v;
    v[0] = (short)f2bf(x[0]); v[1] = (short)f2bf(x[1]);
    v[2] = (short)f2bf(x[2]); v[3] = (short)f2bf(x[3]);
    v[4] = (short)f2bf(y[0]); v[5] = (short)f2bf(y[1]);
    v[6] = (short)f2bf(y[2]); v[7] = (short)f2bf(y[3]);
    return v;
  };

  // one BK=64 tile: 2 MFMA k-steps x 4 d-tiles
  auto compute = [&](int t, int buf) {
#pragma unroll
    for (int kk = 0; kk < 2; ++kk) {
      const int g0 = kk * 8 + lhi * 2;                // A granule (4 floats each)
      const int s0 = g0 ^ l15;
      const f32x4 x = *(const f32x4*)&alds[buf][wave * 16 + l15][s0 * 4];
      const f32x4 y = *(const f32x4*)&alds[buf][wave * 16 + l15][(s0 ^ 1) * 4];
      s16x8 a = cvtA(x, y);
#pragma unroll
      for (int dt = 0; dt < 4; ++dt) {
        const int sm = (kk * 4 + lhi) ^ (l15 & 7);
        s16x8 b = *(const s16x8*)&mlds2[buf][dt * 16 + l15][sm * 8];
        acc[dt] = __builtin_amdgcn_mfma_f32_16x16x32_bf16(a, b, acc[dt], 0, 0, 0);
      }
    }
  };

  // ---- prologue: tiles 0 and 1 in flight (12 DMAs) ----
  stageA(0, 0); stageM(0, 0);
  stageA(1, 1); stageM(1, 1);
  __builtin_amdgcn_sched_barrier(0);
  asm volatile("s_waitcnt vmcnt(6)");        // tile 0's 6 DMAs done (tile 1 in flight)
  __builtin_amdgcn_sched_barrier(0);
  __builtin_amdgcn_s_barrier();              // all waves' tile-0 staging complete
  __builtin_amdgcn_sched_barrier(0);

  for (int t = 0; t < ITERS - 1; ++t) {
    const int buf = t & 1;
    compute(t, buf);
    __builtin_amdgcn_sched_barrier(0);
    __builtin_amdgcn_s_barrier();            // all reads of buf done -> safe to re-stage
    __builtin_amdgcn_sched_barrier(0);
    const int tc = (t + 2 < ITERS) ? t + 2 : ITERS - 1;  // dup-stage keeps vmem count uniform
    stageA(tc, buf); stageM(tc, buf);        // 6 vmem into freed buffer
    __builtin_amdgcn_sched_barrier(0);
    asm volatile("s_waitcnt vmcnt(6)");      // oldest 6 = tile(t+1)'s DMAs complete
    __builtin_amdgcn_sched_barrier(0);
    __builtin_amdgcn_s_barrier();            // ALL waves' tile(t+1) staging complete
    __builtin_amdgcn_sched_barrier(0);
  }
  compute(ITERS - 1, (ITERS - 1) & 1);
  asm volatile("s_waitcnt vmcnt(0)");        // drain trailing dup stage

  // epilogue: C layout col=lane&15, row=(lane>>4)*4+i (m89-verified)
#pragma unroll
  for (int dt = 0; dt < 4; ++dt) {
    const int d = dt * 16 + l15;
#pragma unroll
    for (int i = 0; i < 4; ++i) {
      const int v = v0 + wave * 16 + lhi * 4 + i;
      if (v < NN) atomicAdd(&out[(size_t)v * DD + d], acc[dt][i]);
    }
  }
}

extern "C" void kernel_launch(void* const* d_in, const int* in_sizes, int n_in,
                              void* d_out, int out_size, void* d_ws, size_t ws_size,
                              hipStream_t stream) {
  const float* H    = (const float*)d_in[0];
  const float* A1   = (const float*)d_in[1];
  const float* A2   = (const float*)d_in[2];
  const float* A3   = (const float*)d_in[3];
  const float* W1   = (const float*)d_in[4];
  const float* W2   = (const float*)d_in[5];
  const float* W3   = (const float*)d_in[6];
  const float* bias = (const float*)d_in[7];
  float* out = (float*)d_out;
  unsigned short* mt = (unsigned short*)d_ws;  // M_T[3][64][KP] bf16 = 3.75 MB

  prep_kernel<<<dim3(KP / 128, 3), 256, 0, stream>>>(H, W1, W2, W3, mt);
  init_out_kernel<<<dim3((NN * DD + 255) / 256), 256, 0, stream>>>(bias, out);
  gcn_main<<<dim3((NN + BM - 1) / BM, SPLITS, 3), 256, 0, stream>>>(A1, A2, A3, mt, out);
}

// Round 10
// 291.333 us; speedup vs baseline: 1.0226x; 1.0226x over previous
//
#include <hip/hip_runtime.h>

// Problem constants
static constexpr int NN = 10000;   // nodes
static constexpr int DD = 64;      // in/out dim
static constexpr int KP = 10240;   // padded K for M_T
static constexpr int KC = 2560;    // K per block (4-way split over grid.y)
static constexpr int BM = 64;      // rows per block

typedef __attribute__((ext_vector_type(4))) float f32x4;
typedef __attribute__((ext_vector_type(8))) short s16x8;
typedef __attribute__((ext_vector_type(4))) unsigned short u16x4;

__device__ __forceinline__ unsigned short f2bf(float f) {
  unsigned u = __float_as_uint(f);
  return (unsigned short)((u + 0x7fffu + ((u >> 16) & 1u)) >> 16);
}

__device__ __forceinline__ void g2l16(const void* g, void* l) {
  __builtin_amdgcn_global_load_lds((const __attribute__((address_space(1))) unsigned int*)g,
                                   (__attribute__((address_space(3))) unsigned int*)l, 16, 0, 0);
}

// ---------- prep: M_T[r][d][k] = bf16( sum_j H[k][j] * W_r[d][j] ), zero-padded to KP ----------
__global__ void prep_kernel(const float* __restrict__ H,
                            const float* __restrict__ W1,
                            const float* __restrict__ W2,
                            const float* __restrict__ W3,
                            unsigned short* __restrict__ mt) {
  const int r = blockIdx.y;
  const float* W = (r == 0) ? W1 : (r == 1) ? W2 : W3;
  const int wave = threadIdx.x >> 6;
  const int lane = threadIdx.x & 63;
  f32x4 wr[16];
#pragma unroll
  for (int i = 0; i < 16; ++i) wr[i] = *(const f32x4*)&W[lane * 64 + i * 4];
  unsigned short* orow = mt + ((size_t)r * 64 + lane) * KP;
  const int kbase = blockIdx.x * 128 + wave * 32;
  for (int i = 0; i < 32; ++i) {
    const int k = kbase + i;
    if (k < NN) {
      float s = 0.f;
#pragma unroll
      for (int j = 0; j < 16; ++j) {
        f32x4 h = *(const f32x4*)&H[(size_t)k * 64 + j * 4];
        s += h[0] * wr[j][0] + h[1] * wr[j][1] + h[2] * wr[j][2] + h[3] * wr[j][3];
      }
      orow[k] = f2bf(s);
    } else {
      orow[k] = 0;
    }
  }
}

// ---------- init: out[v][d] = bias[d] ----------
__global__ void init_out_kernel(const float* __restrict__ bias, float* __restrict__ out) {
  const int i = blockIdx.x * 256 + threadIdx.x;
  if (i < NN * DD) out[i] = bias[i & 63];
}

// ---------- main: out += A_r[:, kchunk] @ M_r[kchunk, :]  (bf16 MFMA) ----------
// MIXED-PATH A/B test: blocks with blockIdx.y<2 stream A via vector reg loads
// (R6 body); blocks with blockIdx.y>=2 stream A via global_load_lds DMA (R9 body).
// Co-resident blocks drive both read paths concurrently -> discriminates
// shared vs separate per-CU outstanding-read pools.
__global__ __launch_bounds__(256, 2) void gcn_main(const float* __restrict__ A1,
                                                   const float* __restrict__ A2,
                                                   const float* __restrict__ A3,
                                                   const unsigned short* __restrict__ mt,
                                                   float* __restrict__ out) {
  __shared__ __align__(1024) char smem[65536];

  const int r = blockIdx.z;
  const int sy = blockIdx.y;
  const float* A = (r == 0) ? A1 : (r == 1) ? A2 : A3;
  const unsigned short* mtr = mt + (size_t)r * 64 * KP;

  const int wave = threadIdx.x >> 6;
  const int lane = threadIdx.x & 63;
  const int l15 = lane & 15;
  const int lhi = lane >> 4;
  const int v0 = blockIdx.x * BM;
  const int k0 = sy * KC;

  f32x4 acc[4] = {{0.f,0.f,0.f,0.f},{0.f,0.f,0.f,0.f},{0.f,0.f,0.f,0.f},{0.f,0.f,0.f,0.f}};

  if (sy < 2) {
    // ================= PATH A: reg-burst staging (R6 body), BK=128, 20 iters ==========
    constexpr int BK = 128, ITERS = 20;
    auto mldsM = (unsigned short (*)[64][128])(smem);          // [2][64][128] 32 KB
    auto mldsA = (unsigned short (*)[64][128])(smem + 32768);  // [2][64][128] 32 KB

    const int l31 = lane & 31;
    const int lh5 = lane >> 5;

    const float* rowPtr[8];
    int wOff[8];
#pragma unroll
    for (int j = 0; j < 8; ++j) {
      const int rloc = wave * 16 + 2 * j + lh5;
      int vr = v0 + rloc; if (vr > NN - 1) vr = NN - 1;
      rowPtr[j] = A + (size_t)vr * NN;
      wOff[j] = rloc * 256 + (((l31 >> 1) ^ (rloc & 15)) * 16) + (lane & 1) * 8;
    }
    int rOffA[4], rOffM[4][4];
#pragma unroll
    for (int kk = 0; kk < 4; ++kk) {
      rOffA[kk] = (wave * 16 + l15) * 256 + (((kk * 4 + lhi) ^ l15) * 16);
#pragma unroll
      for (int dt = 0; dt < 4; ++dt)
        rOffM[kk][dt] = (dt * 16 + l15) * 256 + (((kk * 4 + lhi) ^ l15) * 16);
    }

    f32x4 ar[8];

    auto stageM = [&](int t, int buf) {
      const int kb = k0 + t * BK;
#pragma unroll
      for (int j = 0; j < 4; ++j) {
        const int row16 = 4 * j + (lane >> 4);
        const int rowabs = wave * 16 + row16;
        const unsigned short* src = mtr + (size_t)rowabs * KP + kb + (((lane & 15) ^ row16) << 3);
        g2l16(src, &mldsM[buf][wave * 16 + 4 * j][0]);
      }
    };
    auto issueA = [&](int kb) {
      int koff = kb + l31 * 4;
      if (koff > NN - 4) koff = NN - 4;
      const float* p0 = rowPtr[0] + koff; const float* p1 = rowPtr[1] + koff;
      const float* p2 = rowPtr[2] + koff; const float* p3 = rowPtr[3] + koff;
      const float* p4 = rowPtr[4] + koff; const float* p5 = rowPtr[5] + koff;
      const float* p6 = rowPtr[6] + koff; const float* p7 = rowPtr[7] + koff;
      asm volatile(
        "global_load_dwordx4 %0, %8, off\n\t"
        "global_load_dwordx4 %1, %9, off\n\t"
        "global_load_dwordx4 %2, %10, off\n\t"
        "global_load_dwordx4 %3, %11, off\n\t"
        "global_load_dwordx4 %4, %12, off\n\t"
        "global_load_dwordx4 %5, %13, off\n\t"
        "global_load_dwordx4 %6, %14, off\n\t"
        "global_load_dwordx4 %7, %15, off"
        : "=&v"(ar[0]), "=&v"(ar[1]), "=&v"(ar[2]), "=&v"(ar[3]),
          "=&v"(ar[4]), "=&v"(ar[5]), "=&v"(ar[6]), "=&v"(ar[7])
        : "v"(p0), "v"(p1), "v"(p2), "v"(p3), "v"(p4), "v"(p5), "v"(p6), "v"(p7));
    };
    auto cvtWrite = [&](int buf, int kb) {
      if (kb + BK > NN) {
        if (kb + l31 * 4 > NN - 4) {
#pragma unroll
          for (int j = 0; j < 8; ++j) ar[j] = (f32x4){0.f, 0.f, 0.f, 0.f};
        }
      }
      char* base = (char*)&mldsA[0][0][0] + buf * 32768 / 2;  // [buf][64][128] stride 16384 B
#pragma unroll
      for (int j = 0; j < 8; ++j) {
        u16x4 c;
        c[0] = f2bf(ar[j][0]); c[1] = f2bf(ar[j][1]);
        c[2] = f2bf(ar[j][2]); c[3] = f2bf(ar[j][3]);
        *(u16x4*)(base + wOff[j]) = c;
      }
    };

    issueA(k0);
    __builtin_amdgcn_sched_barrier(0);
    stageM(0, 0);
    __builtin_amdgcn_sched_barrier(0);
    asm volatile("s_waitcnt vmcnt(4)");
    __builtin_amdgcn_sched_barrier(0);
    cvtWrite(0, k0);
    __builtin_amdgcn_sched_barrier(0);
    asm volatile("s_waitcnt vmcnt(0)");
    __builtin_amdgcn_sched_barrier(0);
    __builtin_amdgcn_s_barrier();

    for (int t = 0; t < ITERS; ++t) {
      const int buf = t & 1;
      const int tn = (t + 1 < ITERS) ? t + 1 : t;
      const int kbn = k0 + tn * BK;
      issueA(kbn);
      __builtin_amdgcn_sched_barrier(0);
      stageM(tn, buf ^ 1);
      __builtin_amdgcn_sched_barrier(0);
      {
        const char* aBase = (const char*)&mldsA[0][0][0] + buf * 16384;
        const char* mBase = (const char*)&mldsM[0][0][0] + buf * 16384;
#pragma unroll
        for (int kk = 0; kk < 4; ++kk) {
          s16x8 a = *(const s16x8*)(aBase + rOffA[kk]);
#pragma unroll
          for (int dt = 0; dt < 4; ++dt) {
            s16x8 b = *(const s16x8*)(mBase + rOffM[kk][dt]);
            acc[dt] = __builtin_amdgcn_mfma_f32_16x16x32_bf16(a, b, acc[dt], 0, 0, 0);
          }
        }
      }
      __builtin_amdgcn_sched_barrier(0);
      asm volatile("s_waitcnt vmcnt(4)");
      __builtin_amdgcn_sched_barrier(0);
      cvtWrite(buf ^ 1, kbn);
      __builtin_amdgcn_sched_barrier(0);
      asm volatile("s_waitcnt vmcnt(0)");
      __builtin_amdgcn_sched_barrier(0);
      __builtin_amdgcn_s_barrier();
    }
  } else {
    // ================= PATH B: global_load_lds DMA staging (R9 body), BK=64, 40 iters ==
    constexpr int BK = 64, ITERS = 40;
    auto alds  = (float (*)[64][64])(smem);                    // [2][64][64] f32 32 KB
    auto mlds2 = (unsigned short (*)[64][64])(smem + 32768);   // [2][64][64] bf16 16 KB

    auto stageA = [&](int t, int buf) {
      const int kb = k0 + t * BK;
#pragma unroll
      for (int j = 0; j < 4; ++j) {
        const int row16 = 4 * j + lhi;
        int vr = v0 + wave * 16 + row16;
        if (vr > NN - 1) vr = NN - 1;
        int colf = kb + ((l15 ^ row16) << 2);
        if (colf > NN - 4) colf = NN - 4;   // OOB-k dup: killed by M=0 pad
        g2l16(A + (size_t)vr * NN + colf, &alds[buf][wave * 16 + 4 * j][0]);
      }
    };
    auto stageM = [&](int t, int buf) {
      const int kb = k0 + t * BK;
#pragma unroll
      for (int j = 0; j < 2; ++j) {
        const int row16 = 8 * j + (lane >> 3);
        const int gsm = (lane & 7) ^ (lane >> 3);
        g2l16(mtr + (size_t)(wave * 16 + row16) * KP + kb + gsm * 8,
              &mlds2[buf][wave * 16 + 8 * j][0]);
      }
    };
    auto cvtA = [&](const f32x4& x, const f32x4& y) -> s16x8 {
      s16x8 v;
      v[0] = (short)f2bf(x[0]); v[1] = (short)f2bf(x[1]);
      v[2] = (short)f2bf(x[2]); v[3] = (short)f2bf(x[3]);
      v[4] = (short)f2bf(y[0]); v[5] = (short)f2bf(y[1]);
      v[6] = (short)f2bf(y[2]); v[7] = (short)f2bf(y[3]);
      return v;
    };
    auto compute = [&](int t, int buf) {
#pragma unroll
      for (int kk = 0; kk < 2; ++kk) {
        const int g0 = kk * 8 + lhi * 2;
        const int s0 = g0 ^ l15;
        const f32x4 x = *(const f32x4*)&alds[buf][wave * 16 + l15][s0 * 4];
        const f32x4 y = *(const f32x4*)&alds[buf][wave * 16 + l15][(s0 ^ 1) * 4];
        s16x8 a = cvtA(x, y);
#pragma unroll
        for (int dt = 0; dt < 4; ++dt) {
          const int sm = (kk * 4 + lhi) ^ (l15 & 7);
          s16x8 b = *(const s16x8*)&mlds2[buf][dt * 16 + l15][sm * 8];
          acc[dt] = __builtin_amdgcn_mfma_f32_16x16x32_bf16(a, b, acc[dt], 0, 0, 0);
        }
      }
    };

    stageA(0, 0); stageM(0, 0);
    stageA(1, 1); stageM(1, 1);
    __builtin_amdgcn_sched_barrier(0);
    asm volatile("s_waitcnt vmcnt(6)");
    __builtin_amdgcn_sched_barrier(0);
    __builtin_amdgcn_s_barrier();
    __builtin_amdgcn_sched_barrier(0);

    for (int t = 0; t < ITERS - 1; ++t) {
      const int buf = t & 1;
      compute(t, buf);
      __builtin_amdgcn_sched_barrier(0);
      __builtin_amdgcn_s_barrier();
      __builtin_amdgcn_sched_barrier(0);
      const int tc = (t + 2 < ITERS) ? t + 2 : ITERS - 1;
      stageA(tc, buf); stageM(tc, buf);
      __builtin_amdgcn_sched_barrier(0);
      asm volatile("s_waitcnt vmcnt(6)");
      __builtin_amdgcn_sched_barrier(0);
      __builtin_amdgcn_s_barrier();
      __builtin_amdgcn_sched_barrier(0);
    }
    compute(ITERS - 1, (ITERS - 1) & 1);
    asm volatile("s_waitcnt vmcnt(0)");
  }

  // epilogue: C layout col=lane&15, row=(lane>>4)*4+i (m89-verified)
#pragma unroll
  for (int dt = 0; dt < 4; ++dt) {
    const int d = dt * 16 + l15;
#pragma unroll
    for (int i = 0; i < 4; ++i) {
      const int v = v0 + wave * 16 + lhi * 4 + i;
      if (v < NN) atomicAdd(&out[(size_t)v * DD + d], acc[dt][i]);
    }
  }
}

extern "C" void kernel_launch(void* const* d_in, const int* in_sizes, int n_in,
                              void* d_out, int out_size, void* d_ws, size_t ws_size,
                              hipStream_t stream) {
  const float* H    = (const float*)d_in[0];
  const float* A1   = (const float*)d_in[1];
  const float* A2   = (const float*)d_in[2];
  const float* A3   = (const float*)d_in[3];
  const float* W1   = (const float*)d_in[4];
  const float* W2   = (const float*)d_in[5];
  const float* W3   = (const float*)d_in[6];
  const float* bias = (const float*)d_in[7];
  float* out = (float*)d_out;
  unsigned short* mt = (unsigned short*)d_ws;  // M_T[3][64][KP] bf16 = 3.75 MB

  prep_kernel<<<dim3(KP / 128, 3), 256, 0, stream>>>(H, W1, W2, W3, mt);
  init_out_kernel<<<dim3((NN * DD + 255) / 256), 256, 0, stream>>>(bias, out);
  // y<2: reg-burst path on K [0,5120); y>=2: DMA path on K [5120,10240).
  gcn_main<<<dim3((NN + BM - 1) / BM, 4, 3), 256, 0, stream>>>(A1, A2, A3, mt, out);
}